// Round 1
// baseline (141.949 us; speedup 1.0000x reference)
//
#include <hip/hip_runtime.h>
#include <hip/hip_bf16.h>
#include <math.h>

// Model_58488864637193:
//   h = ring_windows(x, 121)            [8,4096,484]
//   h = tanh(h @ W0 + b0)               [8,4096,32]
//   h = h @ W1 + b1                     [8,4096,512]   \
//   h = h @ Ws + bs                     [8,4096,4096]   > NO activation between
//   h = h @ Wr + br                     [8,4096,4]     /  => collapse to h @ Wc + bc
//   h = ring_windows(h, 5)              [8,4096,20]
//   h = relu(h @ W2 + b2)               [8,4096,32]
//   out = h @ W3 + b3                   [8,4096,4]
//
// Algebraic collapse: Wc = W1 @ Ws @ Wr  [32,4], bc = (b1@Ws + bs)@Wr + br [4].
// Precompute order: T = [Ws; bs] @ Wr ([513,4], cheap), then Wc = W1 @ T.
// Work drops 141 GFLOP -> ~1.1 GFLOP (dominated by the 484->32 windowed layer).

#define L_SEQ 4096
#define TL    128   // output rows per stage1 block

// ---------------- precomp1: T[513][4] = [Ws; bs] @ Wr ----------------
__global__ __launch_bounds__(256) void precomp1_kernel(
    const float* __restrict__ Ws, const float* __restrict__ bs,
    const float* __restrict__ Wr, float* __restrict__ T) {
  const int k   = blockIdx.x;    // 0..512 ; k==512 -> bs row
  const int tid = threadIdx.x;
  const float* row = (k < 512) ? (Ws + (size_t)k * 4096) : bs;
  const float4* Wr4 = (const float4*)Wr;
  float a0 = 0.f, a1 = 0.f, a2 = 0.f, a3 = 0.f;
  for (int m = tid; m < 4096; m += 256) {
    const float rv = row[m];
    const float4 w = Wr4[m];
    a0 = fmaf(rv, w.x, a0); a1 = fmaf(rv, w.y, a1);
    a2 = fmaf(rv, w.z, a2); a3 = fmaf(rv, w.w, a3);
  }
  __shared__ float red[256][4];
  red[tid][0] = a0; red[tid][1] = a1; red[tid][2] = a2; red[tid][3] = a3;
  __syncthreads();
  for (int s = 128; s > 0; s >>= 1) {
    if (tid < s) {
      red[tid][0] += red[tid + s][0]; red[tid][1] += red[tid + s][1];
      red[tid][2] += red[tid + s][2]; red[tid][3] += red[tid + s][3];
    }
    __syncthreads();
  }
  if (tid == 0) {
    T[k*4+0] = red[0][0]; T[k*4+1] = red[0][1];
    T[k*4+2] = red[0][2]; T[k*4+3] = red[0][3];
  }
}

// ---------------- precomp2: WcBc[132] = {Wc[32][4] row-major, bc[4]} ----------------
__global__ __launch_bounds__(256) void precomp2_kernel(
    const float* __restrict__ W1, const float* __restrict__ b1,
    const float* __restrict__ br, const float* __restrict__ T,
    float* __restrict__ WcBc) {
  const int tid = threadIdx.x;
  if (tid >= 132) return;
  const int i = tid >> 2;   // 0..32 (32 => bias row b1)
  const int j = tid & 3;
  const float* v = (i < 32) ? (W1 + (size_t)i * 512) : b1;
  float acc = 0.f;
  for (int m = 0; m < 512; ++m) acc = fmaf(v[m], T[m*4 + j], acc);
  if (i == 32) acc += T[512*4 + j] + br[j];
  WcBc[tid] = acc;   // Wc[k][j] at k*4+j (k<32), bc[j] at 128+j
}

// ---------------- stage1: y[b][l][0..3] = tanh(win121(x) @ W0 + b0) @ Wc + bc ----
__global__ __launch_bounds__(256) void stage1_kernel(
    const float* __restrict__ x, const float* __restrict__ W0,
    const float* __restrict__ b0, const float* __restrict__ WcBc,
    float* __restrict__ y) {
  __shared__ float4 sW0v[484 * 8];      // 484x32 floats = 61952 B
  __shared__ float4 sXv[TL + 120];      // 248 positions x 4 ch = 3968 B
  __shared__ float  sY[256][4];         // per-thread partial y, 4096 B
  __shared__ float  sWc[132];           // Wc + bc

  const int b    = blockIdx.x >> 5;     // 8 batches x 32 tiles
  const int tile = blockIdx.x & 31;
  const int l0   = tile * TL;
  const int tid  = threadIdx.x;

  // stage W0 (global, L2-resident after first blocks) -> LDS
  const float4* W0v = (const float4*)W0;
  for (int i = tid; i < 484 * 8; i += 256) sW0v[i] = W0v[i];
  // stage x halo window: positions (l0-120 .. l0+TL-1) mod 4096
  const float4* xv = (const float4*)(x + (size_t)b * L_SEQ * 4);
  for (int i = tid; i < TL + 120; i += 256)
    sXv[i] = xv[(l0 - 120 + i) & (L_SEQ - 1)];
  if (tid < 132) sWc[tid] = WcBc[tid];
  __syncthreads();

  const int row  = tid & (TL - 1);      // 0..127
  const int ngrp = tid >> 7;            // 0/1 -> neurons [16*ngrp, 16*ngrp+16)
  const int n0   = ngrp * 16;
  const int n04  = ngrp * 4;            // float4 offset into a 32-float W0 row

  float acc[16];
#pragma unroll
  for (int n = 0; n < 16; ++n) acc[n] = b0[n0 + n];

  for (int d = 0; d < 121; ++d) {
    const float4 xc = sXv[row + d];
    const float4* w4 = sW0v + d * 32 + n04;   // row (d*4+c) starts at c*8 float4
#pragma unroll
    for (int c = 0; c < 4; ++c) {
      const float xs = ((const float*)&xc)[c];
#pragma unroll
      for (int q = 0; q < 4; ++q) {
        const float4 w = w4[c * 8 + q];
        acc[q*4+0] = fmaf(xs, w.x, acc[q*4+0]);
        acc[q*4+1] = fmaf(xs, w.y, acc[q*4+1]);
        acc[q*4+2] = fmaf(xs, w.z, acc[q*4+2]);
        acc[q*4+3] = fmaf(xs, w.w, acc[q*4+3]);
      }
    }
  }

  // tanh + fold through Wc (partial over this thread's 16 neurons)
  float yp[4] = {0.f, 0.f, 0.f, 0.f};
#pragma unroll
  for (int n = 0; n < 16; ++n) {
    const float h = tanhf(acc[n]);
#pragma unroll
    for (int j = 0; j < 4; ++j) yp[j] = fmaf(h, sWc[(n0 + n) * 4 + j], yp[j]);
  }
#pragma unroll
  for (int j = 0; j < 4; ++j) sY[tid][j] = yp[j];
  __syncthreads();

  if (tid < TL) {
    float4 out;
    ((float*)&out)[0] = sY[tid][0] + sY[tid + 128][0] + sWc[128 + 0];
    ((float*)&out)[1] = sY[tid][1] + sY[tid + 128][1] + sWc[128 + 1];
    ((float*)&out)[2] = sY[tid][2] + sY[tid + 128][2] + sWc[128 + 2];
    ((float*)&out)[3] = sY[tid][3] + sY[tid + 128][3] + sWc[128 + 3];
    ((float4*)(y + (size_t)b * L_SEQ * 4))[l0 + tid] = out;
  }
}

// ---------------- stage2: out = relu(win5(y) @ W2 + b2) @ W3 + b3 ----------------
__global__ __launch_bounds__(256) void stage2_kernel(
    const float* __restrict__ y, const float* __restrict__ W2,
    const float* __restrict__ b2, const float* __restrict__ W3,
    const float* __restrict__ b3, float* __restrict__ out) {
  const int g = blockIdx.x * 256 + threadIdx.x;  // 0..32767
  const int b = g >> 12;
  const int l = g & (L_SEQ - 1);
  const float4* yv = (const float4*)(y + (size_t)b * L_SEQ * 4);

  float win[20];
#pragma unroll
  for (int j = 0; j < 5; ++j) {
    const float4 v = yv[(l - 4 + j) & (L_SEQ - 1)];
    win[j*4+0] = v.x; win[j*4+1] = v.y; win[j*4+2] = v.z; win[j*4+3] = v.w;
  }

  float h[32];
#pragma unroll
  for (int n = 0; n < 32; ++n) h[n] = b2[n];
  for (int k = 0; k < 20; ++k) {
    const float xs = win[k];
#pragma unroll
    for (int n = 0; n < 32; ++n) h[n] = fmaf(xs, W2[k*32 + n], h[n]);
  }

  float o[4];
#pragma unroll
  for (int j = 0; j < 4; ++j) o[j] = b3[j];
#pragma unroll
  for (int n = 0; n < 32; ++n) {
    const float hv = fmaxf(h[n], 0.f);
#pragma unroll
    for (int j = 0; j < 4; ++j) o[j] = fmaf(hv, W3[n*4 + j], o[j]);
  }
  float4 ov;
  ((float*)&ov)[0] = o[0]; ((float*)&ov)[1] = o[1];
  ((float*)&ov)[2] = o[2]; ((float*)&ov)[3] = o[3];
  ((float4*)out)[g] = ov;
}

extern "C" void kernel_launch(void* const* d_in, const int* in_sizes, int n_in,
                              void* d_out, int out_size, void* d_ws, size_t ws_size,
                              hipStream_t stream) {
  const float* x  = (const float*)d_in[0];   // [8,4096,4]
  const float* W0 = (const float*)d_in[1];   // [484,32]
  const float* b0 = (const float*)d_in[2];   // [32]
  const float* W1 = (const float*)d_in[3];   // [32,512]
  const float* b1 = (const float*)d_in[4];   // [512]
  const float* Ws = (const float*)d_in[5];   // [512,4096]
  const float* bs = (const float*)d_in[6];   // [4096]
  const float* Wr = (const float*)d_in[7];   // [4096,4]
  const float* br = (const float*)d_in[8];   // [4]
  const float* W2 = (const float*)d_in[9];   // [20,32]
  const float* b2 = (const float*)d_in[10];  // [32]
  const float* W3 = (const float*)d_in[11];  // [32,4]
  const float* b3 = (const float*)d_in[12];  // [4]
  float* outp = (float*)d_out;               // [8,4096,4]

  // workspace layout (floats): T[513*4]=2052 @0, WcBc[132] @2052, y[131072] @2304
  float* T    = (float*)d_ws;
  float* WcBc = T + 2052;
  float* y    = (float*)d_ws + 2304;   // 16B-aligned (2304*4 bytes)

  precomp1_kernel<<<513, 256, 0, stream>>>(Ws, bs, Wr, T);
  precomp2_kernel<<<1, 256, 0, stream>>>(W1, b1, br, T, WcBc);
  stage1_kernel<<<256, 256, 0, stream>>>(x, W0, b0, WcBc, y);
  stage2_kernel<<<128, 256, 0, stream>>>(y, W2, b2, W3, b3, outp);
}

// Round 2
// 128.582 us; speedup vs baseline: 1.1040x; 1.1040x over previous
//
#include <hip/hip_runtime.h>
#include <hip/hip_bf16.h>
#include <math.h>

// Model_58488864637193 — algebraic collapse of the 3 stacked linears:
//   Wc = W1 @ (Ws @ Wr)  [32,4],  bc = (b1 @ (Ws@Wr)) + bs@Wr + br  [4]
// Work drops 141 GFLOP -> ~1.1 GFLOP, dominated by the ring-121 484->32 tanh layer.
//
// R1 -> R2: precomp1 wave-per-row shfl reduce; precomp2 parallelized (was a
// serial 512-chain, latency-bound suspect); stage1 TL=64 / 512 blocks for
// 2 blocks/CU (was 1) and fast tanh via __expf.

#define L_SEQ 4096
#define TL    64    // output rows per stage1 block

// ---------------- precomp1: T[513][4] = [Ws; bs] @ Wr ----------------
// one wave per output row; float4 loads; butterfly reduce; no LDS.
__global__ __launch_bounds__(256) void precomp1_kernel(
    const float* __restrict__ Ws, const float* __restrict__ bs,
    const float* __restrict__ Wr, float* __restrict__ T) {
  const int tid  = threadIdx.x;
  const int k    = blockIdx.x * 4 + (tid >> 6);   // wave id = output row
  const int lane = tid & 63;
  if (k >= 513) return;
  const float4* row4 = (const float4*)((k < 512) ? (Ws + (size_t)k * 4096) : bs);
  const float4* Wr4  = (const float4*)Wr;
  float a0 = 0.f, a1 = 0.f, a2 = 0.f, a3 = 0.f;
  for (int m4 = lane; m4 < 1024; m4 += 64) {
    const float4 rv = row4[m4];
#pragma unroll
    for (int c = 0; c < 4; ++c) {
      const float  xs = ((const float*)&rv)[c];
      const float4 w  = Wr4[m4 * 4 + c];
      a0 = fmaf(xs, w.x, a0); a1 = fmaf(xs, w.y, a1);
      a2 = fmaf(xs, w.z, a2); a3 = fmaf(xs, w.w, a3);
    }
  }
#pragma unroll
  for (int off = 32; off > 0; off >>= 1) {
    a0 += __shfl_xor(a0, off); a1 += __shfl_xor(a1, off);
    a2 += __shfl_xor(a2, off); a3 += __shfl_xor(a3, off);
  }
  if (lane == 0) {
    float4 o; o.x = a0; o.y = a1; o.z = a2; o.w = a3;
    ((float4*)T)[k] = o;
  }
}

// ---------------- precomp2: WcBc[132] = {Wc[32][4] row-major, bc[4]} ----------------
// block i handles row i of [W1; b1] (i==32 -> b1); 128 threads, LDS tree-reduce.
__global__ __launch_bounds__(128) void precomp2_kernel(
    const float* __restrict__ W1, const float* __restrict__ b1,
    const float* __restrict__ br, const float* __restrict__ T,
    float* __restrict__ WcBc) {
  const int i   = blockIdx.x;        // 0..32
  const int t   = threadIdx.x;       // 0..127
  const int j   = t & 3;
  const int seg = t >> 2;            // 0..31 -> m in [seg*16, seg*16+16)
  const float4* v4 = (const float4*)((i < 32) ? (W1 + (size_t)i * 512) : b1);
  const float4* T4 = (const float4*)T;
  float acc = 0.f;
#pragma unroll
  for (int q = 0; q < 4; ++q) {
    const int m4 = seg * 4 + q;
    const float4 vv = v4[m4];
#pragma unroll
    for (int c = 0; c < 4; ++c) {
      const float4 trow = T4[m4 * 4 + c];     // T row (4*m4+c)
      acc = fmaf(((const float*)&vv)[c], ((const float*)&trow)[j], acc);
    }
  }
  __shared__ float red[128];
  red[t] = acc;
  __syncthreads();
#pragma unroll
  for (int s = 64; s >= 4; s >>= 1) {
    if (t < s) red[t] += red[t + s];
    __syncthreads();
  }
  if (t < 4) {
    float r = red[t];
    if (i == 32) r += T[512 * 4 + t] + br[t];
    WcBc[(i < 32 ? i * 4 : 128) + t] = r;
  }
}

// ---------------- stage1: y = tanh(win121(x) @ W0 + b0) @ Wc + bc ----------------
// 512 blocks (8 batches x 64 tiles), 256 threads = 64 rows x 4 neuron-groups.
__global__ __launch_bounds__(256, 2) void stage1_kernel(
    const float* __restrict__ x, const float* __restrict__ W0,
    const float* __restrict__ b0, const float* __restrict__ WcBc,
    float* __restrict__ y) {
  __shared__ float4 sW0v[484 * 8];      // 484x32 floats = 61952 B
  __shared__ float4 sXv[TL + 120];      // 184 positions x 4 ch = 2944 B
  __shared__ float  sY[256][4];         // per-thread partial y
  __shared__ float  sWc[132];           // Wc + bc

  const int b    = blockIdx.x >> 6;     // 8 batches x 64 tiles
  const int tile = blockIdx.x & 63;
  const int l0   = tile * TL;
  const int tid  = threadIdx.x;

  const float4* W0v = (const float4*)W0;
  for (int i = tid; i < 484 * 8; i += 256) sW0v[i] = W0v[i];
  const float4* xv = (const float4*)(x + (size_t)b * L_SEQ * 4);
  for (int i = tid; i < TL + 120; i += 256)
    sXv[i] = xv[(l0 - 120 + i) & (L_SEQ - 1)];
  if (tid < 132) sWc[tid] = WcBc[tid];
  __syncthreads();

  const int row  = tid & (TL - 1);      // 0..63
  const int ngrp = tid >> 6;            // 0..3 -> neurons [8*ngrp, 8*ngrp+8)
  const int n0   = ngrp * 8;
  const int n04  = ngrp * 2;            // float4 offset into a 32-float W0 row

  float acc[8];
#pragma unroll
  for (int n = 0; n < 8; ++n) acc[n] = b0[n0 + n];

  for (int d = 0; d < 121; ++d) {
    const float4 xc = sXv[row + d];
    const float4* w4 = sW0v + d * 32 + n04;   // row (d*4+c) starts at (d*4+c)*8
#pragma unroll
    for (int c = 0; c < 4; ++c) {
      const float xs = ((const float*)&xc)[c];
#pragma unroll
      for (int q = 0; q < 2; ++q) {
        const float4 w = w4[c * 8 + q];
        acc[q*4+0] = fmaf(xs, w.x, acc[q*4+0]);
        acc[q*4+1] = fmaf(xs, w.y, acc[q*4+1]);
        acc[q*4+2] = fmaf(xs, w.z, acc[q*4+2]);
        acc[q*4+3] = fmaf(xs, w.w, acc[q*4+3]);
      }
    }
  }

  // fast tanh + fold through Wc (partial over this thread's 8 neurons)
  float yp[4] = {0.f, 0.f, 0.f, 0.f};
#pragma unroll
  for (int n = 0; n < 8; ++n) {
    const float h = 1.f - 2.f / (__expf(2.f * acc[n]) + 1.f);
#pragma unroll
    for (int j = 0; j < 4; ++j) yp[j] = fmaf(h, sWc[(n0 + n) * 4 + j], yp[j]);
  }
#pragma unroll
  for (int j = 0; j < 4; ++j) sY[tid][j] = yp[j];
  __syncthreads();

  if (tid < TL) {
    float4 out;
#pragma unroll
    for (int j = 0; j < 4; ++j)
      ((float*)&out)[j] = sY[tid][j] + sY[tid + 64][j] + sY[tid + 128][j]
                        + sY[tid + 192][j] + sWc[128 + j];
    ((float4*)(y + (size_t)b * L_SEQ * 4))[l0 + tid] = out;
  }
}

// ---------------- stage2: out = relu(win5(y) @ W2 + b2) @ W3 + b3 ----------------
__global__ __launch_bounds__(256) void stage2_kernel(
    const float* __restrict__ y, const float* __restrict__ W2,
    const float* __restrict__ b2, const float* __restrict__ W3,
    const float* __restrict__ b3, float* __restrict__ out) {
  const int g = blockIdx.x * 256 + threadIdx.x;  // 0..32767
  const int b = g >> 12;
  const int l = g & (L_SEQ - 1);
  const float4* yv = (const float4*)(y + (size_t)b * L_SEQ * 4);

  float win[20];
#pragma unroll
  for (int j = 0; j < 5; ++j) {
    const float4 v = yv[(l - 4 + j) & (L_SEQ - 1)];
    win[j*4+0] = v.x; win[j*4+1] = v.y; win[j*4+2] = v.z; win[j*4+3] = v.w;
  }

  float h[32];
#pragma unroll
  for (int n = 0; n < 32; ++n) h[n] = b2[n];
#pragma unroll
  for (int k = 0; k < 20; ++k) {
    const float xs = win[k];
#pragma unroll
    for (int n = 0; n < 32; ++n) h[n] = fmaf(xs, W2[k*32 + n], h[n]);
  }

  float o[4];
#pragma unroll
  for (int j = 0; j < 4; ++j) o[j] = b3[j];
#pragma unroll
  for (int n = 0; n < 32; ++n) {
    const float hv = fmaxf(h[n], 0.f);
#pragma unroll
    for (int j = 0; j < 4; ++j) o[j] = fmaf(hv, W3[n*4 + j], o[j]);
  }
  float4 ov;
  ((float*)&ov)[0] = o[0]; ((float*)&ov)[1] = o[1];
  ((float*)&ov)[2] = o[2]; ((float*)&ov)[3] = o[3];
  ((float4*)out)[g] = ov;
}

extern "C" void kernel_launch(void* const* d_in, const int* in_sizes, int n_in,
                              void* d_out, int out_size, void* d_ws, size_t ws_size,
                              hipStream_t stream) {
  const float* x  = (const float*)d_in[0];   // [8,4096,4]
  const float* W0 = (const float*)d_in[1];   // [484,32]
  const float* b0 = (const float*)d_in[2];   // [32]
  const float* W1 = (const float*)d_in[3];   // [32,512]
  const float* b1 = (const float*)d_in[4];   // [512]
  const float* Ws = (const float*)d_in[5];   // [512,4096]
  const float* bs = (const float*)d_in[6];   // [4096]
  const float* Wr = (const float*)d_in[7];   // [4096,4]
  const float* br = (const float*)d_in[8];   // [4]
  const float* W2 = (const float*)d_in[9];   // [20,32]
  const float* b2 = (const float*)d_in[10];  // [32]
  const float* W3 = (const float*)d_in[11];  // [32,4]
  const float* b3 = (const float*)d_in[12];  // [4]
  float* outp = (float*)d_out;               // [8,4096,4]

  // workspace (floats): T[513*4]=2052 @0, WcBc[132] @2052, y[131072] @2304
  float* T    = (float*)d_ws;
  float* WcBc = T + 2052;
  float* y    = (float*)d_ws + 2304;   // 16B-aligned

  precomp1_kernel<<<129, 256, 0, stream>>>(Ws, bs, Wr, T);
  precomp2_kernel<<<33, 128, 0, stream>>>(W1, b1, br, T, WcBc);
  stage1_kernel<<<512, 256, 0, stream>>>(x, W0, b0, WcBc, y);
  stage2_kernel<<<128, 256, 0, stream>>>(y, W2, b2, W3, b3, outp);
}